// Round 1
// baseline (1082.107 us; speedup 1.0000x reference)
//
#include <hip/hip_runtime.h>
#include <stdint.h>

#define N_NODES 10000
#define N_EDGES 160000
#define E_TOT   170000   // edges + self loops
#define IN_CH   1030
#define HC      1024
#define OUT_CH  49
#define NEG_SLOPE 0.2f
#define LN_EPS 1e-5f

#define MPAD  10112   // 79 * 128
#define K1PAD 1056    // 33 * 32 (1030 padded)

typedef __attribute__((ext_vector_type(8))) __bf16 bf16x8;
typedef __attribute__((ext_vector_type(4))) float floatx4;

static __device__ __forceinline__ unsigned short f2bf(float f) {
  union { float f; uint32_t u; } v; v.f = f;
  uint32_t u = v.u;
  u += 0x7fffu + ((u >> 16) & 1u);   // round-to-nearest-even
  return (unsigned short)(u >> 16);
}

// ---------------- casts / transposes ----------------

__global__ void cast_x_kernel(const float* __restrict__ x, unsigned short* __restrict__ xa) {
  int idx = blockIdx.x * 256 + threadIdx.x;       // over N_NODES * K1PAD
  if (idx >= N_NODES * K1PAD) return;
  int m = idx / K1PAD, k = idx - m * K1PAD;
  float v = (k < IN_CH) ? x[m * IN_CH + k] : 0.f;
  xa[idx] = f2bf(v);
}

// out[n*Kout + k] = (k < Kvalid ? W[k][n] : 0); W col picked from wa/wb by split
__global__ void transpose_cast_kernel(const float* __restrict__ wa, const float* __restrict__ wb,
                                      int split, int lda, int ldb,
                                      int Kvalid, int Kout, unsigned short* __restrict__ out) {
  __shared__ float tile[32][33];
  int n0 = blockIdx.x * 32, k0 = blockIdx.y * 32;
  int tx = threadIdx.x, ty = threadIdx.y;  // 32 x 8
#pragma unroll
  for (int i = 0; i < 4; i++) {
    int k = k0 + ty + i * 8;
    int n = n0 + tx;
    float v = 0.f;
    if (k < Kvalid) v = (n < split) ? wa[(size_t)k * lda + n] : wb[(size_t)k * ldb + (n - split)];
    tile[ty + i * 8][tx] = v;
  }
  __syncthreads();
#pragma unroll
  for (int i = 0; i < 4; i++) {
    int n = n0 + ty + i * 8;
    int k = k0 + tx;
    out[(size_t)n * Kout + k] = f2bf(tile[tx][ty + i * 8]);
  }
}

__global__ void w2t_kernel(const float* __restrict__ w2, float* __restrict__ out) {
  int o = blockIdx.x;            // 49 blocks
  int k = threadIdx.x;           // 256 threads
  out[o * 256 + k] = w2[k * OUT_CH + o];
}

// ---------------- CSR build (group edges by dst) ----------------

__global__ void count_kernel(const int* __restrict__ dstArr, int* __restrict__ counts) {
  int e = blockIdx.x * 256 + threadIdx.x;
  if (e >= E_TOT) return;
  int d = (e < N_EDGES) ? dstArr[e] : (e - N_EDGES);
  atomicAdd(&counts[d], 1);
}

__global__ void scan_kernel(const int* __restrict__ counts, int* __restrict__ row_start) {
  __shared__ int sm[256];
  __shared__ int carry;
  int t = threadIdx.x;
  if (t == 0) { carry = 0; row_start[0] = 0; }
  __syncthreads();
  for (int base = 0; base < N_NODES; base += 256) {
    int v = (base + t < N_NODES) ? counts[base + t] : 0;
    sm[t] = v; __syncthreads();
    for (int s = 1; s < 256; s <<= 1) {
      int add = (t >= s) ? sm[t - s] : 0;
      __syncthreads();
      sm[t] += add;
      __syncthreads();
    }
    if (base + t < N_NODES) row_start[base + t + 1] = carry + sm[t];
    __syncthreads();
    if (t == 0) carry += sm[255];
    __syncthreads();
  }
}

__global__ void scatter_kernel(const int* __restrict__ dstArr, const int* __restrict__ row_start,
                               int* __restrict__ cursor, int* __restrict__ csr) {
  int e = blockIdx.x * 256 + threadIdx.x;
  if (e >= E_TOT) return;
  int d = (e < N_EDGES) ? dstArr[e] : (e - N_EDGES);
  int pos = atomicAdd(&cursor[d], 1);
  csr[row_start[d] + pos] = e;
}

// ---------------- bf16 MFMA GEMM (m97-style: 128x128 tile, BK=32, 4 waves) ----------------
// A: [M][K] bf16 (rows padded to tile), Bt: [N][K] bf16 (pre-transposed), C: [M][ldc] fp32
// bias[n] = n < bsplit ? blo[n] : bhi[n-bsplit]; ACT: 0=none, 1=ELU
template <int ACT>
__global__ __launch_bounds__(256) void gemm_bf16(
    const unsigned short* __restrict__ A, const unsigned short* __restrict__ Bt,
    float* __restrict__ C, const float* __restrict__ blo, const float* __restrict__ bhi,
    int M, int K, int ldc, int bsplit)
{
  __shared__ __align__(16) unsigned short As[128 * 32];
  __shared__ __align__(16) unsigned short Bs[128 * 32];
  const int t = threadIdx.x;
  const int w = t >> 6, lane = t & 63;
  const int tile_m = blockIdx.x * 128, tile_n = blockIdx.y * 128;

  floatx4 acc[4][4] = {};

  const int q0 = w * 128 + lane;   // 16B-chunk ids this thread stages (j=0 and j=1)
  const int q1 = q0 + 64;
  const unsigned short* gA0 = A + (size_t)(tile_m + (q0 >> 2)) * K + (q0 & 3) * 8;
  const unsigned short* gA1 = A + (size_t)(tile_m + (q1 >> 2)) * K + (q1 & 3) * 8;
  const unsigned short* gB0 = Bt + (size_t)(tile_n + (q0 >> 2)) * K + (q0 & 3) * 8;
  const unsigned short* gB1 = Bt + (size_t)(tile_n + (q1 >> 2)) * K + (q1 & 3) * 8;
  unsigned short* lA0 = As + w * 1024;
  unsigned short* lA1 = As + w * 1024 + 512;
  unsigned short* lB0 = Bs + w * 1024;
  unsigned short* lB1 = Bs + w * 1024 + 512;

  const int wm = (w >> 1) * 64, wn = (w & 1) * 64;
  const int lrow = lane & 15, lk = (lane >> 4) * 8;

  for (int k0 = 0; k0 < K; k0 += 32) {
    __builtin_amdgcn_global_load_lds((const __attribute__((address_space(1))) void*)gA0,
                                     (__attribute__((address_space(3))) void*)lA0, 16, 0, 0);
    __builtin_amdgcn_global_load_lds((const __attribute__((address_space(1))) void*)gA1,
                                     (__attribute__((address_space(3))) void*)lA1, 16, 0, 0);
    __builtin_amdgcn_global_load_lds((const __attribute__((address_space(1))) void*)gB0,
                                     (__attribute__((address_space(3))) void*)lB0, 16, 0, 0);
    __builtin_amdgcn_global_load_lds((const __attribute__((address_space(1))) void*)gB1,
                                     (__attribute__((address_space(3))) void*)lB1, 16, 0, 0);
    gA0 += 32; gA1 += 32; gB0 += 32; gB1 += 32;
    __syncthreads();
    bf16x8 a[4], b[4];
#pragma unroll
    for (int mi = 0; mi < 4; mi++)
      a[mi] = *(const bf16x8*)(As + (wm + mi * 16 + lrow) * 32 + lk);
#pragma unroll
    for (int ni = 0; ni < 4; ni++)
      b[ni] = *(const bf16x8*)(Bs + (wn + ni * 16 + lrow) * 32 + lk);
#pragma unroll
    for (int mi = 0; mi < 4; mi++)
#pragma unroll
      for (int ni = 0; ni < 4; ni++)
        acc[mi][ni] = __builtin_amdgcn_mfma_f32_16x16x32_bf16(a[mi], b[ni], acc[mi][ni], 0, 0, 0);
    __syncthreads();
  }

  const int rbase = (lane >> 4) * 4;
#pragma unroll
  for (int mi = 0; mi < 4; mi++) {
#pragma unroll
    for (int r = 0; r < 4; r++) {
      int m = tile_m + wm + mi * 16 + rbase + r;
      if (m >= M) continue;
#pragma unroll
      for (int ni = 0; ni < 4; ni++) {
        int n = tile_n + wn + ni * 16 + lrow;
        float v = acc[mi][ni][r] + (n < bsplit ? blo[n] : bhi[n - bsplit]);
        if (ACT == 1) v = v > 0.f ? v : expm1f(v);
        C[(size_t)m * ldc + n] = v;
      }
    }
  }
}

// ---------------- GATv2 edge scores: e[e][h] = sum_c lrelu(xl[s]+xr[d]) * att[h][c] --------

__global__ __launch_bounds__(256) void escore_kernel(
    const float* __restrict__ xlr, const float* __restrict__ att,
    const int* __restrict__ srcArr, const int* __restrict__ dstArr,
    float* __restrict__ escore)
{
  int e = blockIdx.x * 4 + (threadIdx.x >> 6);
  if (e >= E_TOT) return;
  int lane = threadIdx.x & 63;
  int s, d;
  if (e < N_EDGES) { s = srcArr[e]; d = dstArr[e]; }
  else { s = e - N_EDGES; d = s; }
  const float* xl = xlr + (size_t)s * 2048 + lane * 16;
  const float* xr = xlr + (size_t)d * 2048 + 1024 + lane * 16;
  const float* at = att + lane * 16;   // == h*256 + (lane&15)*16
  float acc = 0.f;
#pragma unroll
  for (int j = 0; j < 4; j++) {
    float4 a = *(const float4*)(xl + j * 4);
    float4 b = *(const float4*)(xr + j * 4);
    float4 wv = *(const float4*)(at + j * 4);
    float s0 = a.x + b.x; s0 = s0 > 0.f ? s0 : NEG_SLOPE * s0; acc += s0 * wv.x;
    float s1 = a.y + b.y; s1 = s1 > 0.f ? s1 : NEG_SLOPE * s1; acc += s1 * wv.y;
    float s2 = a.z + b.z; s2 = s2 > 0.f ? s2 : NEG_SLOPE * s2; acc += s2 * wv.z;
    float s3 = a.w + b.w; s3 = s3 > 0.f ? s3 : NEG_SLOPE * s3; acc += s3 * wv.w;
  }
#pragma unroll
  for (int m = 8; m >= 1; m >>= 1) acc += __shfl_xor(acc, m, 64);
  if ((lane & 15) == 0) escore[e * 4 + (lane >> 4)] = acc;
}

// ---------------- segment softmax + aggregation per dst node ----------------

__global__ __launch_bounds__(256) void agg_kernel(
    const float* __restrict__ xlr, const float* __restrict__ escore,
    const int* __restrict__ srcArr,
    const int* __restrict__ csr, const int* __restrict__ row_start,
    const float* __restrict__ conv_bias, float* __restrict__ out)
{
  int d = blockIdx.x;
  int t = threadIdx.x;
  int start = row_start[d];
  int deg = row_start[d + 1] - start;
  __shared__ float red[256];
  __shared__ float smax[4], srden[4];

  int h4 = t & 3;
  float lmax = -3.4e38f;
  for (int i = (t >> 2); i < deg; i += 64)
    lmax = fmaxf(lmax, escore[csr[start + i] * 4 + h4]);
  red[t] = lmax; __syncthreads();
  for (int s = 128; s >= 4; s >>= 1) {
    if (t < s) red[t] = fmaxf(red[t], red[t + s]);
    __syncthreads();
  }
  if (t < 4) smax[t] = red[t];
  __syncthreads();

  float mh = smax[h4];
  float lsum = 0.f;
  for (int i = (t >> 2); i < deg; i += 64)
    lsum += expf(escore[csr[start + i] * 4 + h4] - mh);
  red[t] = lsum; __syncthreads();
  for (int s = 128; s >= 4; s >>= 1) {
    if (t < s) red[t] += red[t + s];
    __syncthreads();
  }
  if (t < 4) srden[t] = 1.f / (red[t] + 1e-16f);
  __syncthreads();

  int h = t >> 6;
  float mx = smax[h], rd = srden[h];
  float4 acc = {0.f, 0.f, 0.f, 0.f};
  for (int i = 0; i < deg; i++) {
    int e = csr[start + i];
    int s_ = (e < N_EDGES) ? srcArr[e] : (e - N_EDGES);
    float al = expf(escore[e * 4 + h] - mx) * rd;
    float4 xv = *(const float4*)(xlr + (size_t)s_ * 2048 + t * 4);
    acc.x += al * xv.x; acc.y += al * xv.y; acc.z += al * xv.z; acc.w += al * xv.w;
  }
  float4 bv = *(const float4*)(conv_bias + t * 4);
  float4 o = {acc.x + bv.x, acc.y + bv.y, acc.z + bv.z, acc.w + bv.w};
  *(float4*)(out + (size_t)d * 1024 + t * 4) = o;
}

// ---------------- LayerNorm + ELU -> bf16 ----------------

__global__ __launch_bounds__(256) void ln_elu_bf16_kernel(
    const float* __restrict__ in, const float* __restrict__ w, const float* __restrict__ b,
    unsigned short* __restrict__ out)
{
  int node = blockIdx.x, t = threadIdx.x;
  const float* row = in + (size_t)node * 1024;
  float4 v = *(const float4*)(row + t * 4);
  __shared__ float r1[256], r2[256];
  r1[t] = v.x + v.y + v.z + v.w;
  r2[t] = v.x * v.x + v.y * v.y + v.z * v.z + v.w * v.w;
  __syncthreads();
  for (int s = 128; s >= 1; s >>= 1) {
    if (t < s) { r1[t] += r1[t + s]; r2[t] += r2[t + s]; }
    __syncthreads();
  }
  float mean = r1[0] * (1.f / 1024.f);
  float var = r2[0] * (1.f / 1024.f) - mean * mean;
  float rstd = rsqrtf(var + LN_EPS);
  float4 wv = *(const float4*)(w + t * 4);
  float4 bv = *(const float4*)(b + t * 4);
  float o0 = (v.x - mean) * rstd * wv.x + bv.x; o0 = o0 > 0.f ? o0 : expm1f(o0);
  float o1 = (v.y - mean) * rstd * wv.y + bv.y; o1 = o1 > 0.f ? o1 : expm1f(o1);
  float o2 = (v.z - mean) * rstd * wv.z + bv.z; o2 = o2 > 0.f ? o2 : expm1f(o2);
  float o3 = (v.w - mean) * rstd * wv.w + bv.w; o3 = o3 > 0.f ? o3 : expm1f(o3);
  ushort4 u;
  u.x = f2bf(o0); u.y = f2bf(o1); u.z = f2bf(o2); u.w = f2bf(o3);
  *(ushort4*)(out + (size_t)node * 1024 + t * 4) = u;
}

// ---------------- final tiny GEMM: out[node][49] = h3 . w2t + b2 ----------------

__global__ __launch_bounds__(64) void cls2_kernel(
    const float* __restrict__ h3, const float* __restrict__ w2t,
    const float* __restrict__ b2, float* __restrict__ out)
{
  __shared__ float row[256];
  int node = blockIdx.x, t = threadIdx.x;
  *(float4*)(row + t * 4) = *(const float4*)(h3 + (size_t)node * 256 + t * 4);
  __syncthreads();
  if (t < OUT_CH) {
    const float* wr = w2t + t * 256;
    float acc = b2[t];
#pragma unroll 4
    for (int k = 0; k < 256; k += 4) {
      float4 a = *(const float4*)(row + k);
      float4 wv = *(const float4*)(wr + k);
      acc += a.x * wv.x + a.y * wv.y + a.z * wv.z + a.w * wv.w;
    }
    out[node * OUT_CH + t] = acc;
  }
}

// ---------------- launch ----------------

extern "C" void kernel_launch(void* const* d_in, const int* in_sizes, int n_in,
                              void* d_out, int out_size, void* d_ws, size_t ws_size,
                              hipStream_t stream)
{
  const float* x       = (const float*)d_in[0];
  const int*   ei      = (const int*)d_in[1];
  const float* c1_wl   = (const float*)d_in[2];
  const float* c1_bl   = (const float*)d_in[3];
  const float* c1_wr   = (const float*)d_in[4];
  const float* c1_br   = (const float*)d_in[5];
  const float* c1_att  = (const float*)d_in[6];
  const float* c1_bias = (const float*)d_in[7];
  const float* ln1_w   = (const float*)d_in[8];
  const float* ln1_b   = (const float*)d_in[9];
  const float* c2_wl   = (const float*)d_in[10];
  const float* c2_bl   = (const float*)d_in[11];
  const float* c2_wr   = (const float*)d_in[12];
  const float* c2_br   = (const float*)d_in[13];
  const float* c2_att  = (const float*)d_in[14];
  const float* c2_bias = (const float*)d_in[15];
  const float* ln2_w   = (const float*)d_in[16];
  const float* ln2_b   = (const float*)d_in[17];
  const float* cls_w1  = (const float*)d_in[18];
  const float* cls_b1  = (const float*)d_in[19];
  const float* cls_w2  = (const float*)d_in[20];
  const float* cls_b2  = (const float*)d_in[21];

  const int* srcArr = ei;
  const int* dstArr = ei + N_EDGES;

  char* ws = (char*)d_ws;
  size_t off = 0;
  auto alloc = [&](size_t bytes) { void* p = ws + off; off += (bytes + 255) & ~(size_t)255; return p; };
  unsigned short* xa      = (unsigned short*)alloc((size_t)MPAD * K1PAD * 2);
  unsigned short* wt1     = (unsigned short*)alloc((size_t)2048 * K1PAD * 2);
  unsigned short* wt2     = (unsigned short*)alloc((size_t)2048 * 1024 * 2);
  unsigned short* wtc1    = (unsigned short*)alloc((size_t)256 * 1024 * 2);
  float*          w2t     = (float*)alloc((size_t)OUT_CH * 256 * 4);
  float*          xlr     = (float*)alloc((size_t)N_NODES * 2048 * 4);
  float*          convout = (float*)alloc((size_t)N_NODES * 1024 * 4);
  unsigned short* hb      = (unsigned short*)alloc((size_t)MPAD * 1024 * 2);
  float*          escore  = (float*)alloc((size_t)E_TOT * 4 * 4);
  int*            counts  = (int*)alloc(N_NODES * 4);
  int*            cursor  = (int*)alloc(N_NODES * 4);
  int*            rstart  = (int*)alloc((N_NODES + 1) * 4);
  int*            csr     = (int*)alloc(E_TOT * 4);
  float*          h3      = convout;   // alias: convout dead after ln2, h3 born at gemm3
  (void)in_sizes; (void)n_in; (void)out_size; (void)ws_size;

  hipMemsetAsync(counts, 0, N_NODES * 4, stream);
  hipMemsetAsync(cursor, 0, N_NODES * 4, stream);

  // prep
  cast_x_kernel<<<(N_NODES * K1PAD + 255) / 256, 256, 0, stream>>>(x, xa);
  transpose_cast_kernel<<<dim3(64, 33), dim3(32, 8), 0, stream>>>(c1_wl, c1_wr, 1024, 1024, 1024, IN_CH, K1PAD, wt1);
  transpose_cast_kernel<<<dim3(64, 32), dim3(32, 8), 0, stream>>>(c2_wl, c2_wr, 1024, 1024, 1024, 1024, 1024, wt2);
  transpose_cast_kernel<<<dim3(8, 32), dim3(32, 8), 0, stream>>>(cls_w1, cls_w1, 256, 256, 256, 1024, 1024, wtc1);
  w2t_kernel<<<OUT_CH, 256, 0, stream>>>(cls_w2, w2t);

  // CSR by dst
  count_kernel<<<(E_TOT + 255) / 256, 256, 0, stream>>>(dstArr, counts);
  scan_kernel<<<1, 256, 0, stream>>>(counts, rstart);
  scatter_kernel<<<(E_TOT + 255) / 256, 256, 0, stream>>>(dstArr, rstart, cursor, csr);

  // layer 1
  gemm_bf16<0><<<dim3(79, 16), 256, 0, stream>>>(xa, wt1, xlr, c1_bl, c1_br, N_NODES, K1PAD, 2048, 1024);
  escore_kernel<<<(E_TOT + 3) / 4, 256, 0, stream>>>(xlr, c1_att, srcArr, dstArr, escore);
  agg_kernel<<<N_NODES, 256, 0, stream>>>(xlr, escore, srcArr, csr, rstart, c1_bias, convout);
  ln_elu_bf16_kernel<<<N_NODES, 256, 0, stream>>>(convout, ln1_w, ln1_b, hb);

  // layer 2
  gemm_bf16<0><<<dim3(79, 16), 256, 0, stream>>>(hb, wt2, xlr, c2_bl, c2_br, N_NODES, 1024, 2048, 1024);
  escore_kernel<<<(E_TOT + 3) / 4, 256, 0, stream>>>(xlr, c2_att, srcArr, dstArr, escore);
  agg_kernel<<<N_NODES, 256, 0, stream>>>(xlr, escore, srcArr, csr, rstart, c2_bias, convout);
  ln_elu_bf16_kernel<<<N_NODES, 256, 0, stream>>>(convout, ln2_w, ln2_b, hb);

  // classifier
  gemm_bf16<1><<<dim3(79, 2), 256, 0, stream>>>(hb, wtc1, h3, cls_b1, cls_b1, N_NODES, 1024, 256, 1024);
  cls2_kernel<<<N_NODES, 64, 0, stream>>>(h3, w2t, cls_b2, (float*)d_out);
}

// Round 2
// 704.344 us; speedup vs baseline: 1.5363x; 1.5363x over previous
//
#include <hip/hip_runtime.h>
#include <stdint.h>

#define N_NODES 10000
#define N_EDGES 160000
#define E_TOT   170000   // edges + self loops
#define IN_CH   1030
#define HC      1024
#define OUT_CH  49
#define NEG_SLOPE 0.2f
#define LN_EPS 1e-5f

#define MPAD  10112   // 79 * 128
#define K1PAD 1056    // 33 * 32 (1030 padded)

typedef __attribute__((ext_vector_type(8))) __bf16 bf16x8;
typedef __attribute__((ext_vector_type(4))) float floatx4;

static __device__ __forceinline__ unsigned short f2bf(float f) {
  union { float f; uint32_t u; } v; v.f = f;
  uint32_t u = v.u;
  u += 0x7fffu + ((u >> 16) & 1u);   // round-to-nearest-even
  return (unsigned short)(u >> 16);
}
static __device__ __forceinline__ float bf2f(unsigned short u) {
  union { uint32_t u; float f; } v; v.u = ((uint32_t)u) << 16; return v.f;
}

// ---------------- casts / transposes ----------------

__global__ void cast_x_kernel(const float* __restrict__ x, unsigned short* __restrict__ xa) {
  int idx = blockIdx.x * 256 + threadIdx.x;       // over N_NODES * K1PAD
  if (idx >= N_NODES * K1PAD) return;
  int m = idx / K1PAD, k = idx - m * K1PAD;
  float v = (k < IN_CH) ? x[m * IN_CH + k] : 0.f;
  xa[idx] = f2bf(v);
}

// out[n*Kout + k] = (k < Kvalid ? W[k][n] : 0); W col picked from wa/wb by split
__global__ void transpose_cast_kernel(const float* __restrict__ wa, const float* __restrict__ wb,
                                      int split, int lda, int ldb,
                                      int Kvalid, int Kout, unsigned short* __restrict__ out) {
  __shared__ float tile[32][33];
  int n0 = blockIdx.x * 32, k0 = blockIdx.y * 32;
  int tx = threadIdx.x, ty = threadIdx.y;  // 32 x 8
#pragma unroll
  for (int i = 0; i < 4; i++) {
    int k = k0 + ty + i * 8;
    int n = n0 + tx;
    float v = 0.f;
    if (k < Kvalid) v = (n < split) ? wa[(size_t)k * lda + n] : wb[(size_t)k * ldb + (n - split)];
    tile[ty + i * 8][tx] = v;
  }
  __syncthreads();
#pragma unroll
  for (int i = 0; i < 4; i++) {
    int n = n0 + ty + i * 8;
    int k = k0 + tx;
    out[(size_t)n * Kout + k] = f2bf(tile[tx][ty + i * 8]);
  }
}

__global__ void w2t_kernel(const float* __restrict__ w2, float* __restrict__ out) {
  int o = blockIdx.x;            // 49 blocks
  int k = threadIdx.x;           // 256 threads
  out[o * 256 + k] = w2[k * OUT_CH + o];
}

// ---------------- CSR build (group edges by dst) ----------------

__global__ void count_kernel(const int* __restrict__ dstArr, int* __restrict__ counts) {
  int e = blockIdx.x * 256 + threadIdx.x;
  if (e >= E_TOT) return;
  int d = (e < N_EDGES) ? dstArr[e] : (e - N_EDGES);
  atomicAdd(&counts[d], 1);
}

// two-level exclusive scan, 256 threads, 40 elems/thread serial
__global__ __launch_bounds__(256) void scan_kernel(const int* __restrict__ counts,
                                                   int* __restrict__ rstart) {
  __shared__ int sm[256];
  int t = threadIdx.x;
  int b0 = t * 40;
  int b1 = b0 + 40; if (b1 > N_NODES) b1 = N_NODES; if (b0 > N_NODES) b0 = N_NODES;
  int s = 0;
  for (int i = b0; i < b1; i++) s += counts[i];
  sm[t] = s; __syncthreads();
  for (int st = 1; st < 256; st <<= 1) {
    int add = (t >= st) ? sm[t - st] : 0;
    __syncthreads();
    sm[t] += add;
    __syncthreads();
  }
  int run = sm[t] - s;   // exclusive prefix of this thread's chunk
  for (int i = b0; i < b1; i++) { rstart[i] = run; run += counts[i]; }
  if (t == 255) rstart[N_NODES] = run;
}

__global__ void scatter_kernel(const int* __restrict__ dstArr, const int* __restrict__ row_start,
                               int* __restrict__ cursor, int* __restrict__ csr) {
  int e = blockIdx.x * 256 + threadIdx.x;
  if (e >= E_TOT) return;
  int d = (e < N_EDGES) ? dstArr[e] : (e - N_EDGES);
  int pos = atomicAdd(&cursor[d], 1);
  csr[row_start[d] + pos] = e;
}

// ---------------- bf16 MFMA GEMM (m97-style: 128x128 tile, BK=32, 4 waves) ----------------
// A: [M][K] bf16 (rows padded to tile), Bt: [N][K] bf16 (pre-transposed)
// MODE 0: Cf[m*ldc+n] = v + bias
// MODE 1: ELU(v + bias) -> Cf
// MODE 2: n<1024 -> Cb[m*1024+n] = bf16(v+bias); else Cf[m*1024+n-1024] = v+bias
template <int MODE>
__global__ __launch_bounds__(256) void gemm_bf16(
    const unsigned short* __restrict__ A, const unsigned short* __restrict__ Bt,
    float* __restrict__ Cf, unsigned short* __restrict__ Cb,
    const float* __restrict__ blo, const float* __restrict__ bhi,
    int M, int K, int ldc, int bsplit)
{
  __shared__ __align__(16) unsigned short As[128 * 32];
  __shared__ __align__(16) unsigned short Bs[128 * 32];
  const int t = threadIdx.x;
  const int w = t >> 6, lane = t & 63;
  const int tile_m = blockIdx.x * 128, tile_n = blockIdx.y * 128;

  floatx4 acc[4][4] = {};

  const int q0 = w * 128 + lane;   // 16B-chunk ids this thread stages
  const int q1 = q0 + 64;
  const unsigned short* gA0 = A + (size_t)(tile_m + (q0 >> 2)) * K + (q0 & 3) * 8;
  const unsigned short* gA1 = A + (size_t)(tile_m + (q1 >> 2)) * K + (q1 & 3) * 8;
  const unsigned short* gB0 = Bt + (size_t)(tile_n + (q0 >> 2)) * K + (q0 & 3) * 8;
  const unsigned short* gB1 = Bt + (size_t)(tile_n + (q1 >> 2)) * K + (q1 & 3) * 8;
  unsigned short* lA0 = As + w * 1024;
  unsigned short* lA1 = As + w * 1024 + 512;
  unsigned short* lB0 = Bs + w * 1024;
  unsigned short* lB1 = Bs + w * 1024 + 512;

  const int wm = (w >> 1) * 64, wn = (w & 1) * 64;
  const int lrow = lane & 15, lk = (lane >> 4) * 8;

  for (int k0 = 0; k0 < K; k0 += 32) {
    __builtin_amdgcn_global_load_lds((const __attribute__((address_space(1))) void*)gA0,
                                     (__attribute__((address_space(3))) void*)lA0, 16, 0, 0);
    __builtin_amdgcn_global_load_lds((const __attribute__((address_space(1))) void*)gA1,
                                     (__attribute__((address_space(3))) void*)lA1, 16, 0, 0);
    __builtin_amdgcn_global_load_lds((const __attribute__((address_space(1))) void*)gB0,
                                     (__attribute__((address_space(3))) void*)lB0, 16, 0, 0);
    __builtin_amdgcn_global_load_lds((const __attribute__((address_space(1))) void*)gB1,
                                     (__attribute__((address_space(3))) void*)lB1, 16, 0, 0);
    gA0 += 32; gA1 += 32; gB0 += 32; gB1 += 32;
    __syncthreads();
    bf16x8 a[4], b[4];
#pragma unroll
    for (int mi = 0; mi < 4; mi++)
      a[mi] = *(const bf16x8*)(As + (wm + mi * 16 + lrow) * 32 + lk);
#pragma unroll
    for (int ni = 0; ni < 4; ni++)
      b[ni] = *(const bf16x8*)(Bs + (wn + ni * 16 + lrow) * 32 + lk);
#pragma unroll
    for (int mi = 0; mi < 4; mi++)
#pragma unroll
      for (int ni = 0; ni < 4; ni++)
        acc[mi][ni] = __builtin_amdgcn_mfma_f32_16x16x32_bf16(a[mi], b[ni], acc[mi][ni], 0, 0, 0);
    __syncthreads();
  }

  const int rbase = (lane >> 4) * 4;
#pragma unroll
  for (int mi = 0; mi < 4; mi++) {
#pragma unroll
    for (int r = 0; r < 4; r++) {
      int m = tile_m + wm + mi * 16 + rbase + r;
      if (m >= M) continue;
#pragma unroll
      for (int ni = 0; ni < 4; ni++) {
        int n = tile_n + wn + ni * 16 + lrow;
        float v = acc[mi][ni][r] + (n < bsplit ? blo[n] : bhi[n - bsplit]);
        if (MODE == 0) {
          Cf[(size_t)m * ldc + n] = v;
        } else if (MODE == 1) {
          Cf[(size_t)m * ldc + n] = v > 0.f ? v : expm1f(v);
        } else {  // split: xl -> bf16, xr -> fp32
          if (n < 1024) Cb[(size_t)m * 1024 + n] = f2bf(v);
          else          Cf[(size_t)m * 1024 + (n - 1024)] = v;
        }
      }
    }
  }
}

// ---------------- fused GATv2 edge phase: score + online softmax + aggregate -------------
// block = dst node, 256 threads = 4 waves, wave == head, lane owns 4 channels.
// Zero barriers in the edge loop: per-edge score is a 6-step wave shfl reduction.

__global__ __launch_bounds__(256) void gat_fused_kernel(
    const unsigned short* __restrict__ xlb,  // [N,1024] bf16 source transform
    const float* __restrict__ xrf,           // [N,1024] fp32 target transform
    const float* __restrict__ att,           // [4,256]
    const int* __restrict__ srcArr,
    const int* __restrict__ csr, const int* __restrict__ rstart,
    const float* __restrict__ bias, float* __restrict__ out)
{
  const int d = blockIdx.x;
  const int t = threadIdx.x;
  const int lane = t & 63;
  const int c = (t >> 6) * 256 + lane * 4;   // 4 channels of head (t>>6)

  float4 xr = *(const float4*)(xrf + (size_t)d * 1024 + c);
  float4 aw = *(const float4*)(att + c);
  int start = rstart[d], deg = rstart[d + 1] - start;

  float m = -3.0e38f, l = 0.f;
  float a0 = 0.f, a1 = 0.f, a2 = 0.f, a3 = 0.f;

  for (int i = 0; i < deg; i++) {
    int e = csr[start + i];
    int s = (e < N_EDGES) ? srcArr[e] : (e - N_EDGES);
    ushort4 u = *(const ushort4*)(xlb + (size_t)s * 1024 + c);
    float x0 = bf2f(u.x), x1 = bf2f(u.y), x2 = bf2f(u.z), x3 = bf2f(u.w);
    float s0 = x0 + xr.x; s0 = s0 > 0.f ? s0 : NEG_SLOPE * s0;
    float s1 = x1 + xr.y; s1 = s1 > 0.f ? s1 : NEG_SLOPE * s1;
    float s2 = x2 + xr.z; s2 = s2 > 0.f ? s2 : NEG_SLOPE * s2;
    float s3 = x3 + xr.w; s3 = s3 > 0.f ? s3 : NEG_SLOPE * s3;
    float p = s0 * aw.x + s1 * aw.y + s2 * aw.z + s3 * aw.w;
#pragma unroll
    for (int mm = 32; mm >= 1; mm >>= 1) p += __shfl_xor(p, mm, 64);
    float mn = fmaxf(m, p);
    float sc = __expf(m - mn);     // first iter: exp(-huge) = 0
    float pe = __expf(p - mn);
    a0 = a0 * sc + pe * x0;
    a1 = a1 * sc + pe * x1;
    a2 = a2 * sc + pe * x2;
    a3 = a3 * sc + pe * x3;
    l = l * sc + pe;
    m = mn;
  }

  float rd = 1.f / (l + 1e-16f);
  float4 bv = *(const float4*)(bias + c);
  float4 o = {a0 * rd + bv.x, a1 * rd + bv.y, a2 * rd + bv.z, a3 * rd + bv.w};
  *(float4*)(out + (size_t)d * 1024 + c) = o;
}

// ---------------- LayerNorm + ELU -> bf16 ----------------

__global__ __launch_bounds__(256) void ln_elu_bf16_kernel(
    const float* __restrict__ in, const float* __restrict__ w, const float* __restrict__ b,
    unsigned short* __restrict__ out)
{
  int node = blockIdx.x, t = threadIdx.x;
  const float* row = in + (size_t)node * 1024;
  float4 v = *(const float4*)(row + t * 4);
  __shared__ float r1[256], r2[256];
  r1[t] = v.x + v.y + v.z + v.w;
  r2[t] = v.x * v.x + v.y * v.y + v.z * v.z + v.w * v.w;
  __syncthreads();
  for (int s = 128; s >= 1; s >>= 1) {
    if (t < s) { r1[t] += r1[t + s]; r2[t] += r2[t + s]; }
    __syncthreads();
  }
  float mean = r1[0] * (1.f / 1024.f);
  float var = r2[0] * (1.f / 1024.f) - mean * mean;
  float rstd = rsqrtf(var + LN_EPS);
  float4 wv = *(const float4*)(w + t * 4);
  float4 bv = *(const float4*)(b + t * 4);
  float o0 = (v.x - mean) * rstd * wv.x + bv.x; o0 = o0 > 0.f ? o0 : expm1f(o0);
  float o1 = (v.y - mean) * rstd * wv.y + bv.y; o1 = o1 > 0.f ? o1 : expm1f(o1);
  float o2 = (v.z - mean) * rstd * wv.z + bv.z; o2 = o2 > 0.f ? o2 : expm1f(o2);
  float o3 = (v.w - mean) * rstd * wv.w + bv.w; o3 = o3 > 0.f ? o3 : expm1f(o3);
  ushort4 u;
  u.x = f2bf(o0); u.y = f2bf(o1); u.z = f2bf(o2); u.w = f2bf(o3);
  *(ushort4*)(out + (size_t)node * 1024 + t * 4) = u;
}

// ---------------- final tiny GEMM: out[node][49] = h3 . w2t + b2 ----------------

__global__ __launch_bounds__(64) void cls2_kernel(
    const float* __restrict__ h3, const float* __restrict__ w2t,
    const float* __restrict__ b2, float* __restrict__ out)
{
  __shared__ float row[256];
  int node = blockIdx.x, t = threadIdx.x;
  *(float4*)(row + t * 4) = *(const float4*)(h3 + (size_t)node * 256 + t * 4);
  __syncthreads();
  if (t < OUT_CH) {
    const float* wr = w2t + t * 256;
    float acc = b2[t];
#pragma unroll 4
    for (int k = 0; k < 256; k += 4) {
      float4 a = *(const float4*)(row + k);
      float4 wv = *(const float4*)(wr + k);
      acc += a.x * wv.x + a.y * wv.y + a.z * wv.z + a.w * wv.w;
    }
    out[node * OUT_CH + t] = acc;
  }
}

// ---------------- launch ----------------

extern "C" void kernel_launch(void* const* d_in, const int* in_sizes, int n_in,
                              void* d_out, int out_size, void* d_ws, size_t ws_size,
                              hipStream_t stream)
{
  const float* x       = (const float*)d_in[0];
  const int*   ei      = (const int*)d_in[1];
  const float* c1_wl   = (const float*)d_in[2];
  const float* c1_bl   = (const float*)d_in[3];
  const float* c1_wr   = (const float*)d_in[4];
  const float* c1_br   = (const float*)d_in[5];
  const float* c1_att  = (const float*)d_in[6];
  const float* c1_bias = (const float*)d_in[7];
  const float* ln1_w   = (const float*)d_in[8];
  const float* ln1_b   = (const float*)d_in[9];
  const float* c2_wl   = (const float*)d_in[10];
  const float* c2_bl   = (const float*)d_in[11];
  const float* c2_wr   = (const float*)d_in[12];
  const float* c2_br   = (const float*)d_in[13];
  const float* c2_att  = (const float*)d_in[14];
  const float* c2_bias = (const float*)d_in[15];
  const float* ln2_w   = (const float*)d_in[16];
  const float* ln2_b   = (const float*)d_in[17];
  const float* cls_w1  = (const float*)d_in[18];
  const float* cls_b1  = (const float*)d_in[19];
  const float* cls_w2  = (const float*)d_in[20];
  const float* cls_b2  = (const float*)d_in[21];

  const int* srcArr = ei;
  const int* dstArr = ei + N_EDGES;

  char* ws = (char*)d_ws;
  size_t off = 0;
  auto alloc = [&](size_t bytes) { void* p = ws + off; off += (bytes + 255) & ~(size_t)255; return p; };
  unsigned short* xa      = (unsigned short*)alloc((size_t)MPAD * K1PAD * 2);
  unsigned short* wt1     = (unsigned short*)alloc((size_t)2048 * K1PAD * 2);
  unsigned short* wt2     = (unsigned short*)alloc((size_t)2048 * 1024 * 2);
  unsigned short* wtc1    = (unsigned short*)alloc((size_t)256 * 1024 * 2);
  float*          w2t     = (float*)alloc((size_t)OUT_CH * 256 * 4);
  unsigned short* xlb     = (unsigned short*)alloc((size_t)N_NODES * 1024 * 2);
  float*          xrf     = (float*)alloc((size_t)N_NODES * 1024 * 4);
  float*          convout = (float*)alloc((size_t)N_NODES * 1024 * 4);
  unsigned short* hb      = (unsigned short*)alloc((size_t)MPAD * 1024 * 2);
  int*            counts  = (int*)alloc(N_NODES * 4);
  int*            cursor  = (int*)alloc(N_NODES * 4);
  int*            rstart  = (int*)alloc((N_NODES + 1) * 4);
  int*            csr     = (int*)alloc(E_TOT * 4);
  float*          h3      = convout;   // alias: convout dead after ln2, h3 born at gemm3
  (void)in_sizes; (void)n_in; (void)out_size; (void)ws_size;

  hipMemsetAsync(counts, 0, N_NODES * 4, stream);
  hipMemsetAsync(cursor, 0, N_NODES * 4, stream);

  // prep
  cast_x_kernel<<<(N_NODES * K1PAD + 255) / 256, 256, 0, stream>>>(x, xa);
  transpose_cast_kernel<<<dim3(64, 33), dim3(32, 8), 0, stream>>>(c1_wl, c1_wr, 1024, 1024, 1024, IN_CH, K1PAD, wt1);
  transpose_cast_kernel<<<dim3(64, 32), dim3(32, 8), 0, stream>>>(c2_wl, c2_wr, 1024, 1024, 1024, 1024, 1024, wt2);
  transpose_cast_kernel<<<dim3(8, 32), dim3(32, 8), 0, stream>>>(cls_w1, cls_w1, 256, 256, 256, 1024, 1024, wtc1);
  w2t_kernel<<<OUT_CH, 256, 0, stream>>>(cls_w2, w2t);

  // CSR by dst
  count_kernel<<<(E_TOT + 255) / 256, 256, 0, stream>>>(dstArr, counts);
  scan_kernel<<<1, 256, 0, stream>>>(counts, rstart);
  scatter_kernel<<<(E_TOT + 255) / 256, 256, 0, stream>>>(dstArr, rstart, cursor, csr);

  // layer 1
  gemm_bf16<2><<<dim3(79, 16), 256, 0, stream>>>(xa, wt1, xrf, xlb, c1_bl, c1_br, N_NODES, K1PAD, 0, 1024);
  gat_fused_kernel<<<N_NODES, 256, 0, stream>>>(xlb, xrf, c1_att, srcArr, csr, rstart, c1_bias, convout);
  ln_elu_bf16_kernel<<<N_NODES, 256, 0, stream>>>(convout, ln1_w, ln1_b, hb);

  // layer 2
  gemm_bf16<2><<<dim3(79, 16), 256, 0, stream>>>(hb, wt2, xrf, xlb, c2_bl, c2_br, N_NODES, 1024, 0, 1024);
  gat_fused_kernel<<<N_NODES, 256, 0, stream>>>(xlb, xrf, c2_att, srcArr, csr, rstart, c2_bias, convout);
  ln_elu_bf16_kernel<<<N_NODES, 256, 0, stream>>>(convout, ln2_w, ln2_b, hb);

  // classifier
  gemm_bf16<1><<<dim3(79, 2), 256, 0, stream>>>(hb, wtc1, h3, nullptr, cls_b1, cls_b1, N_NODES, 1024, 256, 1024);
  cls2_kernel<<<N_NODES, 64, 0, stream>>>(h3, w2t, cls_b2, (float*)d_out);
}

// Round 3
// 598.694 us; speedup vs baseline: 1.8074x; 1.1765x over previous
//
#include <hip/hip_runtime.h>
#include <stdint.h>

#define N_NODES 10000
#define N_EDGES 160000
#define E_TOT   170000   // edges + self loops
#define IN_CH   1030
#define HC      1024
#define OUT_CH  49
#define NEG_SLOPE 0.2f
#define LN_EPS 1e-5f

#define MPAD  10112   // 79 * 128
#define K1PAD 1088    // 17 * 64 (1030 padded to BK=64 multiple)

typedef __attribute__((ext_vector_type(8))) __bf16 bf16x8;
typedef __attribute__((ext_vector_type(4))) float floatx4;

static __device__ __forceinline__ unsigned short f2bf(float f) {
  union { float f; uint32_t u; } v; v.f = f;
  uint32_t u = v.u;
  u += 0x7fffu + ((u >> 16) & 1u);   // round-to-nearest-even
  return (unsigned short)(u >> 16);
}
static __device__ __forceinline__ float bf2f(unsigned short u) {
  union { uint32_t u; float f; } v; v.u = ((uint32_t)u) << 16; return v.f;
}

// ---------------- casts / transposes ----------------

__global__ void cast_x_kernel(const float* __restrict__ x, unsigned short* __restrict__ xa) {
  int idx = blockIdx.x * 256 + threadIdx.x;       // over N_NODES * K1PAD
  if (idx >= N_NODES * K1PAD) return;
  int m = idx / K1PAD, k = idx - m * K1PAD;
  float v = (k < IN_CH) ? x[m * IN_CH + k] : 0.f;
  xa[idx] = f2bf(v);
}

// out[n*Kout + k] = (k < Kvalid ? W[k][n] : 0); W col picked from wa/wb by split
__global__ void transpose_cast_kernel(const float* __restrict__ wa, const float* __restrict__ wb,
                                      int split, int lda, int ldb,
                                      int Kvalid, int Kout, unsigned short* __restrict__ out) {
  __shared__ float tile[32][33];
  int n0 = blockIdx.x * 32, k0 = blockIdx.y * 32;
  int tx = threadIdx.x, ty = threadIdx.y;  // 32 x 8
#pragma unroll
  for (int i = 0; i < 4; i++) {
    int k = k0 + ty + i * 8;
    int n = n0 + tx;
    float v = 0.f;
    if (k < Kvalid) v = (n < split) ? wa[(size_t)k * lda + n] : wb[(size_t)k * ldb + (n - split)];
    tile[ty + i * 8][tx] = v;
  }
  __syncthreads();
#pragma unroll
  for (int i = 0; i < 4; i++) {
    int n = n0 + ty + i * 8;
    int k = k0 + tx;
    out[(size_t)n * Kout + k] = f2bf(tile[tx][ty + i * 8]);
  }
}

__global__ void w2t_kernel(const float* __restrict__ w2, float* __restrict__ out) {
  int o = blockIdx.x;            // 49 blocks
  int k = threadIdx.x;           // 256 threads
  out[o * 256 + k] = w2[k * OUT_CH + o];
}

// ---------------- CSR build (group edges by dst) ----------------

__global__ void count_kernel(const int* __restrict__ dstArr, int* __restrict__ counts) {
  int e = blockIdx.x * 256 + threadIdx.x;
  if (e >= E_TOT) return;
  int d = (e < N_EDGES) ? dstArr[e] : (e - N_EDGES);
  atomicAdd(&counts[d], 1);
}

// two-level exclusive scan, 256 threads, 40 elems/thread serial
__global__ __launch_bounds__(256) void scan_kernel(const int* __restrict__ counts,
                                                   int* __restrict__ rstart) {
  __shared__ int sm[256];
  int t = threadIdx.x;
  int b0 = t * 40;
  int b1 = b0 + 40; if (b1 > N_NODES) b1 = N_NODES; if (b0 > N_NODES) b0 = N_NODES;
  int s = 0;
  for (int i = b0; i < b1; i++) s += counts[i];
  sm[t] = s; __syncthreads();
  for (int st = 1; st < 256; st <<= 1) {
    int add = (t >= st) ? sm[t - st] : 0;
    __syncthreads();
    sm[t] += add;
    __syncthreads();
  }
  int run = sm[t] - s;   // exclusive prefix of this thread's chunk
  for (int i = b0; i < b1; i++) { rstart[i] = run; run += counts[i]; }
  if (t == 255) rstart[N_NODES] = run;
}

__global__ void scatter_kernel(const int* __restrict__ dstArr, const int* __restrict__ row_start,
                               int* __restrict__ cursor, int* __restrict__ csr) {
  int e = blockIdx.x * 256 + threadIdx.x;
  if (e >= E_TOT) return;
  int d = (e < N_EDGES) ? dstArr[e] : (e - N_EDGES);
  int pos = atomicAdd(&cursor[d], 1);
  csr[row_start[d] + pos] = e;
}

// ---------------- bf16 MFMA GEMM: 128x128 tile, BK=64, XOR-swizzled LDS ----------------
// A: [M][K] bf16 (rows padded), Bt: [N][K] bf16. K must be a multiple of 64.
// LDS layout: slab of 128 rows x 64 cols; 16B chunk j of row r stored at slot (j ^ (r&7)).
// Staging via global_load_lds (lane-contiguous slots); the XOR permutes which lane loads
// which chunk WITHIN a row (same 128B segment -> coalescing preserved).
// MODE 0: Cf = v+bias; MODE 1: ELU -> Cf; MODE 2: n<1024 -> bf16 Cb, else fp32 Cf.
template <int MODE>
__global__ __launch_bounds__(256) void gemm_bf16(
    const unsigned short* __restrict__ A, const unsigned short* __restrict__ Bt,
    float* __restrict__ Cf, unsigned short* __restrict__ Cb,
    const float* __restrict__ blo, const float* __restrict__ bhi,
    int M, int K, int ldc, int bsplit)
{
  __shared__ __align__(16) unsigned short As[128 * 64];
  __shared__ __align__(16) unsigned short Bs[128 * 64];
  const int t = threadIdx.x;
  const int w = t >> 6, lane = t & 63;
  const int tile_n = blockIdx.x * 128, tile_m = blockIdx.y * 128;   // x = N-tile (16 wide): L2 share

  floatx4 acc[4][4] = {};

  // staging geometry: slot q = p*256 + w*64 + lane; row = q>>3; sj = q&7; gj = sj ^ (row&7)
  const int q = w * 64 + lane;          // 0..255 (p-invariant part)
  const int row0 = q >> 3;              // 0..31; row_p = row0 + p*32 (row&7 p-invariant)
  const int gj = (q & 7) ^ (row0 & 7);
  const unsigned short* gA0 = A  + (size_t)(tile_m + row0) * K + gj * 8;
  const unsigned short* gB0 = Bt + (size_t)(tile_n + row0) * K + gj * 8;

  const int wm = (w >> 1) * 64, wn = (w & 1) * 64;
  const int lrow = lane & 63 & 15, cg0 = (lane >> 4);
  const int sw = lrow & 7;              // row&7 of every fragment row this lane reads

  for (int k0 = 0; k0 < K; k0 += 64) {
#pragma unroll
    for (int p = 0; p < 4; p++) {
      __builtin_amdgcn_global_load_lds(
          (const __attribute__((address_space(1))) void*)(gA0 + (size_t)p * 32 * K),
          (__attribute__((address_space(3))) void*)(As + p * 2048 + w * 512), 16, 0, 0);
      __builtin_amdgcn_global_load_lds(
          (const __attribute__((address_space(1))) void*)(gB0 + (size_t)p * 32 * K),
          (__attribute__((address_space(3))) void*)(Bs + p * 2048 + w * 512), 16, 0, 0);
    }
    gA0 += 64; gB0 += 64;
    __syncthreads();
#pragma unroll
    for (int h = 0; h < 2; h++) {
      const int sc = (h * 4 + cg0) ^ sw;   // swizzled chunk slot
      bf16x8 a[4], b[4];
#pragma unroll
      for (int mi = 0; mi < 4; mi++)
        a[mi] = *(const bf16x8*)(As + (wm + mi * 16 + lrow) * 64 + sc * 8);
#pragma unroll
      for (int ni = 0; ni < 4; ni++)
        b[ni] = *(const bf16x8*)(Bs + (wn + ni * 16 + lrow) * 64 + sc * 8);
#pragma unroll
      for (int mi = 0; mi < 4; mi++)
#pragma unroll
        for (int ni = 0; ni < 4; ni++)
          acc[mi][ni] = __builtin_amdgcn_mfma_f32_16x16x32_bf16(a[mi], b[ni], acc[mi][ni], 0, 0, 0);
    }
    __syncthreads();
  }

  const int rbase = (lane >> 4) * 4;
#pragma unroll
  for (int mi = 0; mi < 4; mi++) {
#pragma unroll
    for (int r = 0; r < 4; r++) {
      int m = tile_m + wm + mi * 16 + rbase + r;
      if (m >= M) continue;
#pragma unroll
      for (int ni = 0; ni < 4; ni++) {
        int n = tile_n + wn + ni * 16 + lrow;
        float v = acc[mi][ni][r] + (n < bsplit ? blo[n] : bhi[n - bsplit]);
        if (MODE == 0) {
          Cf[(size_t)m * ldc + n] = v;
        } else if (MODE == 1) {
          Cf[(size_t)m * ldc + n] = v > 0.f ? v : expm1f(v);
        } else {  // split: xl -> bf16, xr -> fp32
          if (n < 1024) Cb[(size_t)m * 1024 + n] = f2bf(v);
          else          Cf[(size_t)m * 1024 + (n - 1024)] = v;
        }
      }
    }
  }
}

// ---------------- fused GATv2 edge phase + LayerNorm + ELU -> bf16 -------------
// block = dst node, 4 waves, wave == head, lane owns 4 channels. Online softmax,
// 2-edge unroll (overlaps the two shuffle-reduce chains, halves the recurrence).
// Epilogue: row is register-resident -> LN (wave shfl + 1 barrier) + ELU + bf16 store.

__global__ __launch_bounds__(256) void gat_ln_kernel(
    const unsigned short* __restrict__ xlb,  // [N,1024] bf16 source transform
    const float* __restrict__ xrf,           // [N,1024] fp32 target transform
    const float* __restrict__ att,           // [4,256]
    const int* __restrict__ srcArr,
    const int* __restrict__ csr, const int* __restrict__ rstart,
    const float* __restrict__ bias,
    const float* __restrict__ lnw, const float* __restrict__ lnb,
    unsigned short* __restrict__ out)        // [MPAD,1024] bf16
{
  const int d = blockIdx.x;
  const int t = threadIdx.x;
  const int lane = t & 63, wv = t >> 6;
  const int c = wv * 256 + lane * 4;   // 4 channels of head wv

  float4 xr = *(const float4*)(xrf + (size_t)d * 1024 + c);
  float4 aw = *(const float4*)(att + c);
  int start = rstart[d], deg = rstart[d + 1] - start;

  float m = -3.0e38f, l = 0.f;
  float a0 = 0.f, a1 = 0.f, a2 = 0.f, a3 = 0.f;

  int i = 0;
  for (; i + 2 <= deg; i += 2) {
    int e0 = csr[start + i], e1 = csr[start + i + 1];
    int s0 = (e0 < N_EDGES) ? srcArr[e0] : (e0 - N_EDGES);
    int s1 = (e1 < N_EDGES) ? srcArr[e1] : (e1 - N_EDGES);
    ushort4 u0 = *(const ushort4*)(xlb + (size_t)s0 * 1024 + c);
    ushort4 u1 = *(const ushort4*)(xlb + (size_t)s1 * 1024 + c);
    float x0 = bf2f(u0.x), x1 = bf2f(u0.y), x2 = bf2f(u0.z), x3 = bf2f(u0.w);
    float y0 = bf2f(u1.x), y1 = bf2f(u1.y), y2 = bf2f(u1.z), y3 = bf2f(u1.w);
    float v, p0, p1;
    v = x0 + xr.x; v = v > 0.f ? v : NEG_SLOPE * v; p0  = v * aw.x;
    v = x1 + xr.y; v = v > 0.f ? v : NEG_SLOPE * v; p0 += v * aw.y;
    v = x2 + xr.z; v = v > 0.f ? v : NEG_SLOPE * v; p0 += v * aw.z;
    v = x3 + xr.w; v = v > 0.f ? v : NEG_SLOPE * v; p0 += v * aw.w;
    v = y0 + xr.x; v = v > 0.f ? v : NEG_SLOPE * v; p1  = v * aw.x;
    v = y1 + xr.y; v = v > 0.f ? v : NEG_SLOPE * v; p1 += v * aw.y;
    v = y2 + xr.z; v = v > 0.f ? v : NEG_SLOPE * v; p1 += v * aw.z;
    v = y3 + xr.w; v = v > 0.f ? v : NEG_SLOPE * v; p1 += v * aw.w;
#pragma unroll
    for (int mm = 32; mm >= 1; mm >>= 1) {
      p0 += __shfl_xor(p0, mm, 64);
      p1 += __shfl_xor(p1, mm, 64);
    }
    float mn = fmaxf(m, fmaxf(p0, p1));
    float sc = __expf(m - mn);
    float pe0 = __expf(p0 - mn), pe1 = __expf(p1 - mn);
    a0 = a0 * sc + pe0 * x0 + pe1 * y0;
    a1 = a1 * sc + pe0 * x1 + pe1 * y1;
    a2 = a2 * sc + pe0 * x2 + pe1 * y2;
    a3 = a3 * sc + pe0 * x3 + pe1 * y3;
    l = l * sc + pe0 + pe1;
    m = mn;
  }
  if (i < deg) {
    int e0 = csr[start + i];
    int s0 = (e0 < N_EDGES) ? srcArr[e0] : (e0 - N_EDGES);
    ushort4 u0 = *(const ushort4*)(xlb + (size_t)s0 * 1024 + c);
    float x0 = bf2f(u0.x), x1 = bf2f(u0.y), x2 = bf2f(u0.z), x3 = bf2f(u0.w);
    float v, p0;
    v = x0 + xr.x; v = v > 0.f ? v : NEG_SLOPE * v; p0  = v * aw.x;
    v = x1 + xr.y; v = v > 0.f ? v : NEG_SLOPE * v; p0 += v * aw.y;
    v = x2 + xr.z; v = v > 0.f ? v : NEG_SLOPE * v; p0 += v * aw.z;
    v = x3 + xr.w; v = v > 0.f ? v : NEG_SLOPE * v; p0 += v * aw.w;
#pragma unroll
    for (int mm = 32; mm >= 1; mm >>= 1) p0 += __shfl_xor(p0, mm, 64);
    float mn = fmaxf(m, p0);
    float sc = __expf(m - mn), pe0 = __expf(p0 - mn);
    a0 = a0 * sc + pe0 * x0;
    a1 = a1 * sc + pe0 * x1;
    a2 = a2 * sc + pe0 * x2;
    a3 = a3 * sc + pe0 * x3;
    l = l * sc + pe0;
  }

  float rd = 1.f / (l + 1e-16f);
  float4 bv = *(const float4*)(bias + c);
  float o0 = a0 * rd + bv.x, o1 = a1 * rd + bv.y, o2 = a2 * rd + bv.z, o3 = a3 * rd + bv.w;

  // LayerNorm over the 1024 channels held by this block
  __shared__ float ws1[4], ws2[4];
  float s1 = o0 + o1 + o2 + o3;
  float s2 = o0 * o0 + o1 * o1 + o2 * o2 + o3 * o3;
#pragma unroll
  for (int mm = 32; mm >= 1; mm >>= 1) {
    s1 += __shfl_xor(s1, mm, 64);
    s2 += __shfl_xor(s2, mm, 64);
  }
  if (lane == 0) { ws1[wv] = s1; ws2[wv] = s2; }
  __syncthreads();
  float mean = (ws1[0] + ws1[1] + ws1[2] + ws1[3]) * (1.f / 1024.f);
  float var  = (ws2[0] + ws2[1] + ws2[2] + ws2[3]) * (1.f / 1024.f) - mean * mean;
  float rstd = rsqrtf(var + LN_EPS);
  float4 wv4 = *(const float4*)(lnw + c);
  float4 bb  = *(const float4*)(lnb + c);
  float z0 = (o0 - mean) * rstd * wv4.x + bb.x; z0 = z0 > 0.f ? z0 : expm1f(z0);
  float z1 = (o1 - mean) * rstd * wv4.y + bb.y; z1 = z1 > 0.f ? z1 : expm1f(z1);
  float z2 = (o2 - mean) * rstd * wv4.z + bb.z; z2 = z2 > 0.f ? z2 : expm1f(z2);
  float z3 = (o3 - mean) * rstd * wv4.w + bb.w; z3 = z3 > 0.f ? z3 : expm1f(z3);
  ushort4 u;
  u.x = f2bf(z0); u.y = f2bf(z1); u.z = f2bf(z2); u.w = f2bf(z3);
  *(ushort4*)(out + (size_t)d * 1024 + c) = u;
}

// ---------------- final tiny GEMM: out[node][49] = h3 . w2t + b2 ----------------

__global__ __launch_bounds__(64) void cls2_kernel(
    const float* __restrict__ h3, const float* __restrict__ w2t,
    const float* __restrict__ b2, float* __restrict__ out)
{
  __shared__ float row[256];
  int node = blockIdx.x, t = threadIdx.x;
  *(float4*)(row + t * 4) = *(const float4*)(h3 + (size_t)node * 256 + t * 4);
  __syncthreads();
  if (t < OUT_CH) {
    const float* wr = w2t + t * 256;
    float acc = b2[t];
#pragma unroll 4
    for (int k = 0; k < 256; k += 4) {
      float4 a = *(const float4*)(row + k);
      float4 wv = *(const float4*)(wr + k);
      acc += a.x * wv.x + a.y * wv.y + a.z * wv.z + a.w * wv.w;
    }
    out[node * OUT_CH + t] = acc;
  }
}

// ---------------- launch ----------------

extern "C" void kernel_launch(void* const* d_in, const int* in_sizes, int n_in,
                              void* d_out, int out_size, void* d_ws, size_t ws_size,
                              hipStream_t stream)
{
  const float* x       = (const float*)d_in[0];
  const int*   ei      = (const int*)d_in[1];
  const float* c1_wl   = (const float*)d_in[2];
  const float* c1_bl   = (const float*)d_in[3];
  const float* c1_wr   = (const float*)d_in[4];
  const float* c1_br   = (const float*)d_in[5];
  const float* c1_att  = (const float*)d_in[6];
  const float* c1_bias = (const float*)d_in[7];
  const float* ln1_w   = (const float*)d_in[8];
  const float* ln1_b   = (const float*)d_in[9];
  const float* c2_wl   = (const float*)d_in[10];
  const float* c2_bl   = (const float*)d_in[11];
  const float* c2_wr   = (const float*)d_in[12];
  const float* c2_br   = (const float*)d_in[13];
  const float* c2_att  = (const float*)d_in[14];
  const float* c2_bias = (const float*)d_in[15];
  const float* ln2_w   = (const float*)d_in[16];
  const float* ln2_b   = (const float*)d_in[17];
  const float* cls_w1  = (const float*)d_in[18];
  const float* cls_b1  = (const float*)d_in[19];
  const float* cls_w2  = (const float*)d_in[20];
  const float* cls_b2  = (const float*)d_in[21];

  const int* srcArr = ei;
  const int* dstArr = ei + N_EDGES;

  char* ws = (char*)d_ws;
  size_t off = 0;
  auto alloc = [&](size_t bytes) { void* p = ws + off; off += (bytes + 255) & ~(size_t)255; return p; };
  unsigned short* xa      = (unsigned short*)alloc((size_t)MPAD * K1PAD * 2);
  unsigned short* wt1     = (unsigned short*)alloc((size_t)2048 * K1PAD * 2);
  unsigned short* wt2     = (unsigned short*)alloc((size_t)2048 * 1024 * 2);
  unsigned short* wtc1    = (unsigned short*)alloc((size_t)256 * 1024 * 2);
  float*          w2t     = (float*)alloc((size_t)OUT_CH * 256 * 4);
  unsigned short* xlb     = (unsigned short*)alloc((size_t)N_NODES * 1024 * 2);
  float*          xrf     = (float*)alloc((size_t)N_NODES * 1024 * 4);
  float*          h3      = (float*)alloc((size_t)N_NODES * 256 * 4);
  unsigned short* hb      = (unsigned short*)alloc((size_t)MPAD * 1024 * 2);
  int*            counts  = (int*)alloc(N_NODES * 4);
  int*            cursor  = (int*)alloc(N_NODES * 4);
  int*            rstart  = (int*)alloc((N_NODES + 1) * 4);
  int*            csr     = (int*)alloc(E_TOT * 4);
  (void)in_sizes; (void)n_in; (void)out_size; (void)ws_size;

  hipMemsetAsync(counts, 0, N_NODES * 4, stream);
  hipMemsetAsync(cursor, 0, N_NODES * 4, stream);

  // prep
  cast_x_kernel<<<(N_NODES * K1PAD + 255) / 256, 256, 0, stream>>>(x, xa);
  transpose_cast_kernel<<<dim3(64, 34), dim3(32, 8), 0, stream>>>(c1_wl, c1_wr, 1024, 1024, 1024, IN_CH, K1PAD, wt1);
  transpose_cast_kernel<<<dim3(64, 32), dim3(32, 8), 0, stream>>>(c2_wl, c2_wr, 1024, 1024, 1024, 1024, 1024, wt2);
  transpose_cast_kernel<<<dim3(8, 32), dim3(32, 8), 0, stream>>>(cls_w1, cls_w1, 256, 256, 256, 1024, 1024, wtc1);
  w2t_kernel<<<OUT_CH, 256, 0, stream>>>(cls_w2, w2t);

  // CSR by dst
  count_kernel<<<(E_TOT + 255) / 256, 256, 0, stream>>>(dstArr, counts);
  scan_kernel<<<1, 256, 0, stream>>>(counts, rstart);
  scatter_kernel<<<(E_TOT + 255) / 256, 256, 0, stream>>>(dstArr, rstart, cursor, csr);

  // layer 1
  gemm_bf16<2><<<dim3(16, 79), 256, 0, stream>>>(xa, wt1, xrf, xlb, c1_bl, c1_br, N_NODES, K1PAD, 0, 1024);
  gat_ln_kernel<<<N_NODES, 256, 0, stream>>>(xlb, xrf, c1_att, srcArr, csr, rstart, c1_bias, ln1_w, ln1_b, hb);

  // layer 2
  gemm_bf16<2><<<dim3(16, 79), 256, 0, stream>>>(hb, wt2, xrf, xlb, c2_bl, c2_br, N_NODES, 1024, 0, 1024);
  gat_ln_kernel<<<N_NODES, 256, 0, stream>>>(xlb, xrf, c2_att, srcArr, csr, rstart, c2_bias, ln2_w, ln2_b, hb);

  // classifier
  gemm_bf16<1><<<dim3(2, 79), 256, 0, stream>>>(hb, wtc1, h3, nullptr, cls_b1, cls_b1, N_NODES, 1024, 256, 1024);
  cls2_kernel<<<N_NODES, 64, 0, stream>>>(h3, w2t, cls_b2, (float*)d_out);
}